// Round 13
// baseline (330.445 us; speedup 1.0000x reference)
//
#include <hip/hip_runtime.h>
#include <math.h>

// Problem constants (fixed by reference)
#define B_ 2
#define H_ 16
#define L_ 4096
#define D_ 128
#define F_ 64
#define F2_ 128
#define S_ 64
#define N_ 64
#define BH_ 32
#define NBT_ 2048
#define CS_ 4                 // blocks per chunk
#define NCH_ 16               // chunks per (b,h)
#define NCHT_ 512             // BH_ * NCH_
#define EPS_ 1e-6f
#define SCALING_ 0.08838834764831845f  // 128^-0.5

typedef float f32x4 __attribute__((ext_vector_type(4)));
typedef short s16x8 __attribute__((ext_vector_type(8)));

#define MFMA(a, b, c) __builtin_amdgcn_mfma_f32_16x16x32_bf16(a, b, c, 0, 0, 0)

__device__ __forceinline__ short f2bf(float f) {
  unsigned u = __float_as_uint(f);
  u += 0x7fffu + ((u >> 16) & 1u);   // RNE
  return (short)(u >> 16);
}
__device__ __forceinline__ float bf2f(short s) {
  return __uint_as_float(((unsigned)(unsigned short)s) << 16);
}
__device__ __forceinline__ s16x8 pack8(f32x4 a, f32x4 b) {
  s16x8 r;
  r[0] = f2bf(a[0]); r[1] = f2bf(a[1]); r[2] = f2bf(a[2]); r[3] = f2bf(a[3]);
  r[4] = f2bf(b[0]); r[5] = f2bf(b[1]); r[6] = f2bf(b[2]); r[7] = f2bf(b[3]);
  return r;
}

// XOR swizzle: byte ^= (row&7)<<4 within a row; used for LDS images AND the
// VT global layout (one address formula everywhere).
__device__ __forceinline__ s16x8 swz_frag(const short* base, int row, int rowBytes, int colByte) {
  int byte = row * rowBytes + (colByte ^ ((row & 7) << 4));
  return *(const s16x8*)((const char*)base + byte);
}
__device__ __forceinline__ void lds_w16(short* lds, int row, int rowBytes, int colByte, short v) {
  int byte = row * rowBytes + (colByte ^ ((row & 7) << 4));
  *(short*)((char*)lds + byte) = v;
}

// ---------------------------------------------------------------------------
// prep_w: Wt[h][f][d] bf16 (transposed).
// ---------------------------------------------------------------------------
__global__ __launch_bounds__(256)
void prep_w(const float* __restrict__ W, short* __restrict__ Wt)
{
  const int h = blockIdx.x;
  const int tid = threadIdx.x;
  const int f = tid & 63, gq = tid >> 6;
  const float* Wh = W + (size_t)h * D_ * F_;
  short* Wo = Wt + (size_t)h * F_ * D_ + (size_t)f * D_ + gq * 32;
  short buf[32];
#pragma unroll
  for (int j = 0; j < 32; ++j) buf[j] = f2bf(Wh[(size_t)(gq * 32 + j) * F_ + f]);
#pragma unroll
  for (int j2 = 0; j2 < 4; ++j2) {
    s16x8 v;
#pragma unroll
    for (int e = 0; e < 8; ++e) v[e] = buf[j2 * 8 + e];
    *(s16x8*)(Wo + j2 * 8) = v;
  }
}

// ---------------------------------------------------------------------------
// chunksum: per chunk (bh, nc), walk CS_ blocks; per block: V->VTs image
// (+ VT global), u=k@W, phi_k -> phiT, dS MFMA accumulating into PERSISTENT
// acc (the chunk total), z colsum accumulate. Write chunk totals fp32,
// thread-major (coalesced, no transpose).
// ---------------------------------------------------------------------------
__global__ __launch_bounds__(256, 2)
void bslh_chunksum(const float* __restrict__ K, const float* __restrict__ V,
                   const short* __restrict__ Wt, short* __restrict__ VT,
                   f32x4* __restrict__ Sc4, float* __restrict__ Zc)
{
  __shared__ __align__(16) char lds[32 * 1024];
  short* phiT = (short*)lds;              // 16KB [128 f][128B] swizzled
  short* VTs = (short*)(lds + 16384);     // 16KB [128 d][128B] baked layout

  const int c = blockIdx.x;
  const int bh = c / NCH_, nc = c % NCH_;
  const int h = bh % H_;
  const int tid = threadIdx.x;
  const int wave = tid >> 6, lane = tid & 63;
  const int rl = lane & 15, g = lane >> 4, kl = g * 8;
  const int r0 = wave * 16;

  const short* Wh = Wt + (size_t)h * (F_ * D_);
  const f32x4 z4 = {0.f, 0.f, 0.f, 0.f};

  f32x4 acc[2][8];   // persistent chunk-total state
#pragma unroll
  for (int tm = 0; tm < 2; ++tm)
#pragma unroll
    for (int tn = 0; tn < 8; ++tn) acc[tm][tn] = z4;
  float zacc = 0.f;  // per-thread half-colsum accumulator (f = tid>>1)

  for (int j = 0; j < CS_; ++j) {
    const int blk = bh * N_ + nc * CS_ + j;
    const float* Kb = K + (size_t)blk * (S_ * D_);

    // batch-issue V and K loads
    f32x4 vv[8];
    {
      const f32x4* gv = (const f32x4*)(V + (size_t)blk * S_ * D_);
#pragma unroll
      for (int ii = 0; ii < 8; ++ii) vv[ii] = gv[tid + 256 * ii];
    }
    f32x4 kv[8];
    {
      const float* kp = Kb + (size_t)(r0 + rl) * D_ + kl;
#pragma unroll
      for (int i = 0; i < 8; ++i) kv[i] = *(const f32x4*)(kp + (i >> 1) * 32 + (i & 1) * 4);
    }

    // V transpose -> VTs (baked swizzle)
#pragma unroll
    for (int ii = 0; ii < 8; ++ii) {
      int idx = tid + 256 * ii;
      int s = idx >> 5, cc = (idx & 31) * 4;
      float m0 = vv[ii][0], m1 = vv[ii][1], m2 = vv[ii][2], m3 = vv[ii][3];
      float o0 = __shfl_xor(m0, 32, 64);
      float o1 = __shfl_xor(m1, 32, 64);
      float o2 = __shfl_xor(m2, 32, 64);
      float o3 = __shfl_xor(m3, 32, 64);
      if (!(tid & 32)) {
        float m[4] = {m0, m1, m2, m3};
        float o[4] = {o0, o1, o2, o3};
#pragma unroll
        for (int jj = 0; jj < 4; ++jj) {
          int d = cc + jj;
          unsigned pk = (unsigned)(unsigned short)f2bf(m[jj]) |
                        ((unsigned)(unsigned short)f2bf(o[jj]) << 16);
          int byte = d * 128 + ((s * 2) ^ ((d & 7) << 4));
          *(unsigned*)((char*)VTs + byte) = pk;
        }
      }
    }

    // u = k @ W
    s16x8 aq[4];
#pragma unroll
    for (int ks = 0; ks < 4; ++ks) aq[ks] = pack8(kv[2 * ks], kv[2 * ks + 1]);
    f32x4 uacc[4] = {z4, z4, z4, z4};
#pragma unroll
    for (int ks = 0; ks < 4; ++ks) {
#pragma unroll
      for (int tn = 0; tn < 4; ++tn) {
        s16x8 b = *(const s16x8*)(Wh + (size_t)(tn * 16 + rl) * D_ + ks * 32 + kl);
        uacc[tn] = MFMA(aq[ks], b, uacc[tn]);
      }
    }

    // phi_k = [softmax(u), softmax(-u)] -> phiT (transposed, swizzled)
#pragma unroll
    for (int reg = 0; reg < 4; ++reg) {
      float mx = -1e30f, mn = 1e30f;
#pragma unroll
      for (int tn = 0; tn < 4; ++tn) {
        mx = fmaxf(mx, uacc[tn][reg]);
        mn = fminf(mn, uacc[tn][reg]);
      }
#pragma unroll
      for (int o = 1; o <= 8; o <<= 1) {
        mx = fmaxf(mx, __shfl_xor(mx, o, 64));
        mn = fminf(mn, __shfl_xor(mn, o, 64));
      }
      float ep[4], em[4], sp = 0.f, sm = 0.f;
#pragma unroll
      for (int tn = 0; tn < 4; ++tn) {
        ep[tn] = __expf(uacc[tn][reg] - mx); sp += ep[tn];
        em[tn] = __expf(mn - uacc[tn][reg]); sm += em[tn];
      }
#pragma unroll
      for (int o = 1; o <= 8; o <<= 1) {
        sp += __shfl_xor(sp, o, 64);
        sm += __shfl_xor(sm, o, 64);
      }
      const float rp = 1.f / sp, rm = 1.f / sm;
      const int srow = r0 + g * 4 + reg;
#pragma unroll
      for (int tn = 0; tn < 4; ++tn) {
        int f = tn * 16 + rl;
        lds_w16(phiT, f,      2 * S_, srow * 2, f2bf(ep[tn] * rp));
        lds_w16(phiT, f + 64, 2 * S_, srow * 2, f2bf(em[tn] * rm));
      }
    }
    __syncthreads();   // phiT + VTs complete

    // VT global (coalesced copy of the image) — consumed by walk's PV/dS
    {
      float4* dst = (float4*)(VT + (size_t)blk * (D_ * S_));
      const float4* src = (const float4*)VTs;
#pragma unroll
      for (int i = 0; i < 4; ++i) dst[tid + 256 * i] = src[tid + 256 * i];
    }

    // z colsum accumulate (thread owns half of f = tid>>1)
    {
      const int f = tid >> 1, half = tid & 1;
      float z = 0.f;
#pragma unroll
      for (int j2 = 0; j2 < 4; ++j2) {
        s16x8 v = swz_frag(phiT, f, 2 * S_, (half * 32 + j2 * 8) * 2);
#pragma unroll
        for (int e = 0; e < 8; ++e) z += bf2f(v[e]);
      }
      zacc += z;
    }

    // dS accumulate: acc += VTs(d-rows) @ phiT
#pragma unroll
    for (int ks = 0; ks < 2; ++ks) {
      s16x8 a[2];
#pragma unroll
      for (int tm = 0; tm < 2; ++tm)
        a[tm] = swz_frag(VTs, wave * 32 + tm * 16 + rl, 2 * S_, (ks * 32 + kl) * 2);
#pragma unroll
      for (int tn = 0; tn < 8; ++tn) {
        s16x8 b = swz_frag(phiT, tn * 16 + rl, 2 * S_, (ks * 32 + kl) * 2);
#pragma unroll
        for (int tm = 0; tm < 2; ++tm)
          acc[tm][tn] = MFMA(a[tm], b, acc[tm][tn]);
      }
    }
    __syncthreads();   // reads done before next block overwrites images
  }

  // write chunk totals: thread-major f32x4, fully coalesced
  f32x4* So = Sc4 + (size_t)c * 4096;
#pragma unroll
  for (int tm = 0; tm < 2; ++tm)
#pragma unroll
    for (int tn = 0; tn < 8; ++tn)
      So[(tm * 8 + tn) * 256 + tid] = acc[tm][tn];

  {
    float z = zacc + __shfl_xor(zacc, 1, 64);
    if (!(tid & 1)) Zc[(size_t)c * F2_ + (tid >> 1)] = z;
  }
}

// ---------------------------------------------------------------------------
// scanc: exclusive fp32 prefix over the NCH_ chunks of each bh.
// blocks [0,512): S entries; blocks [512,516): Z entries.
// ---------------------------------------------------------------------------
__global__ __launch_bounds__(256)
void bslh_scanc(f32x4* __restrict__ Sc4, f32x4* __restrict__ Zc4)
{
  const int tid = threadIdx.x;
  if (blockIdx.x < 512) {
    const int idx = blockIdx.x * 256 + tid;    // 131072 = 32 bh * 4096
    const int bh = idx >> 12;
    const int e = idx & 4095;
    f32x4* p = Sc4 + (size_t)bh * NCH_ * 4096 + e;
    f32x4 run = {0.f, 0.f, 0.f, 0.f};
#pragma unroll 4
    for (int n = 0; n < NCH_; ++n) {
      f32x4 v = p[(size_t)n * 4096];
      p[(size_t)n * 4096] = run;
      run += v;
    }
  } else {
    const int idx = (blockIdx.x - 512) * 256 + tid;  // 1024 = 32 bh * 32
    const int bh = idx >> 5, e = idx & 31;
    f32x4* p = Zc4 + (size_t)bh * NCH_ * 32 + e;
    f32x4 run = {0.f, 0.f, 0.f, 0.f};
#pragma unroll 4
    for (int n = 0; n < NCH_; ++n) {
      f32x4 v = p[(size_t)n * 32];
      p[(size_t)n * 32] = run;
      run += v;
    }
  }
}

// ---------------------------------------------------------------------------
// walk: per chunk, state lives in acc[2][8] (fp32 MFMA accumulator) and Zl
// (LDS). Per block: repack state->bf16 img; phi_q + scores + phi_k; cl;
// out = (phi@img)*cl + P@V (single write); dS MFMA accumulates into acc.
// ---------------------------------------------------------------------------
__global__ __launch_bounds__(256, 2)
void bslh_walk(const float* __restrict__ Q, const float* __restrict__ K,
               const short* __restrict__ VT, const short* __restrict__ Wt,
               const f32x4* __restrict__ Sc4, const float* __restrict__ Zc,
               const float* __restrict__ alphap, float* __restrict__ Out)
{
  __shared__ __align__(16) short img[F2_ * D_];   // 32KB [128 d][256B] swizzled
  __shared__ __align__(16) short phi[S_ * F2_];   // 16KB wave-private rows
  __shared__ __align__(16) short phiT[F2_ * S_];  // 16KB [128 f][128B]
  __shared__ __align__(16) short Pl[S_ * S_];     // 8KB wave-private rows
  __shared__ float Zl[F2_];

  const int c = blockIdx.x;
  const int bh = c / NCH_, nc = c % NCH_;
  const int h = bh % H_;
  const int tid = threadIdx.x;
  const int wave = tid >> 6, lane = tid & 63;
  const int rl = lane & 15, g = lane >> 4, kl = g * 8;
  const int r0 = wave * 16;

  const short* Wh = Wt + (size_t)h * (F_ * D_);
  const float w = 1.f / (1.f + __expf(-alphap[0]));
  const f32x4 z4 = {0.f, 0.f, 0.f, 0.f};

  // load chunk-prefix state into the accumulator (exact layout round-trip)
  f32x4 acc[2][8];
  {
    const f32x4* Si = Sc4 + (size_t)c * 4096;
#pragma unroll
    for (int tm = 0; tm < 2; ++tm)
#pragma unroll
      for (int tn = 0; tn < 8; ++tn)
        acc[tm][tn] = Si[(tm * 8 + tn) * 256 + tid];
  }
  if (tid < F2_) Zl[tid] = Zc[(size_t)c * F2_ + tid];

  for (int j = 0; j < CS_; ++j) {
    const int blk = bh * N_ + nc * CS_ + j;
    const float* Qb = Q + (size_t)blk * (S_ * D_);
    const float* Kb = K + (size_t)blk * (S_ * D_);
    const short* VTb = VT + (size_t)blk * (D_ * S_);

    // issue q + k(A) loads early; they fly during repack + barrier
    f32x4 qv[8], kv[8];
    {
      const float* qp = Qb + (size_t)(r0 + rl) * D_ + kl;
      const float* kp = Kb + (size_t)(r0 + rl) * D_ + kl;
#pragma unroll
      for (int i = 0; i < 8; ++i) {
        qv[i] = *(const f32x4*)(qp + (i >> 1) * 32 + (i & 1) * 4);
        kv[i] = *(const f32x4*)(kp + (i >> 1) * 32 + (i & 1) * 4);
      }
    }

    // repack state acc -> img (bf16, swizzled) — same mapping as chunksum
#pragma unroll
    for (int tm = 0; tm < 2; ++tm)
#pragma unroll
      for (int tn = 0; tn < 8; ++tn)
#pragma unroll
        for (int reg = 0; reg < 4; ++reg) {
          float v0 = acc[tm][tn][reg];
          float v1 = __shfl_xor(v0, 1, 64);
          if (!(lane & 1)) {
            int drow = wave * 32 + tm * 16 + g * 4 + reg;
            int fcol = tn * 16 + rl;
            unsigned pk = (unsigned)(unsigned short)f2bf(v0) |
                          ((unsigned)(unsigned short)f2bf(v1) << 16);
            int byte = drow * 256 + ((fcol * 2) ^ ((drow & 7) << 4));
            *(unsigned*)((char*)img + byte) = pk;
          }
        }
    __syncthreads();   // img + Zl published

    // fragments
    s16x8 aqq[4], aqk[4];
#pragma unroll
    for (int ks = 0; ks < 4; ++ks) {
      aqq[ks] = pack8(qv[2 * ks], qv[2 * ks + 1]);
      aqk[ks] = pack8(kv[2 * ks], kv[2 * ks + 1]);
    }

    // u_q = q@W and u_k = k@W (shared W fragments), scores = q@k^T
    f32x4 uq[4] = {z4, z4, z4, z4}, uk[4] = {z4, z4, z4, z4};
#pragma unroll
    for (int ks = 0; ks < 4; ++ks) {
#pragma unroll
      for (int tn = 0; tn < 4; ++tn) {
        s16x8 b = *(const s16x8*)(Wh + (size_t)(tn * 16 + rl) * D_ + ks * 32 + kl);
        uq[tn] = MFMA(aqq[ks], b, uq[tn]);
        uk[tn] = MFMA(aqk[ks], b, uk[tn]);
      }
    }
    f32x4 sacc[4] = {z4, z4, z4, z4};
#pragma unroll
    for (int ks = 0; ks < 4; ++ks) {
#pragma unroll
      for (int tn = 0; tn < 4; ++tn) {
        const float* kp = Kb + (size_t)(tn * 16 + rl) * D_ + ks * 32 + kl;
        s16x8 b = pack8(*(const f32x4*)kp, *(const f32x4*)(kp + 4));
        sacc[tn] = MFMA(aqq[ks], b, sacc[tn]);
      }
    }

    // phi_q softmax -> phi (wave-private) + cl via Zl (exclusive state)
    float cl[4];
#pragma unroll
    for (int reg = 0; reg < 4; ++reg) {
      float mx = -1e30f, mn = 1e30f;
#pragma unroll
      for (int tn = 0; tn < 4; ++tn) {
        mx = fmaxf(mx, uq[tn][reg]);
        mn = fminf(mn, uq[tn][reg]);
      }
#pragma unroll
      for (int o = 1; o <= 8; o <<= 1) {
        mx = fmaxf(mx, __shfl_xor(mx, o, 64));
        mn = fminf(mn, __shfl_xor(mn, o, 64));
      }
      float ep[4], em[4], sp = 0.f, sm = 0.f;
#pragma unroll
      for (int tn = 0; tn < 4; ++tn) {
        ep[tn] = __expf(uq[tn][reg] - mx); sp += ep[tn];
        em[tn] = __expf(mn - uq[tn][reg]); sm += em[tn];
      }
#pragma unroll
      for (int o = 1; o <= 8; o <<= 1) {
        sp += __shfl_xor(sp, o, 64);
        sm += __shfl_xor(sm, o, 64);
      }
      const float rp = 1.f / sp, rm = 1.f / sm;
      const int srow = r0 + g * 4 + reg;
      float dp = 0.f;
#pragma unroll
      for (int tn = 0; tn < 4; ++tn) {
        float pv = ep[tn] * rp, mv = em[tn] * rm;
        int f = tn * 16 + rl;
        dp = fmaf(pv, Zl[f], dp);
        dp = fmaf(mv, Zl[f + 64], dp);
        lds_w16(phi, srow, 2 * F2_, f * 2,        f2bf(pv));
        lds_w16(phi, srow, 2 * F2_, (f + 64) * 2, f2bf(mv));
      }
#pragma unroll
      for (int o = 1; o <= 8; o <<= 1) dp += __shfl_xor(dp, o, 64);
      cl[reg] = (1.f - w) / fmaxf(dp, EPS_);
    }

    // phi_k softmax -> phiT (cross-wave columns)
#pragma unroll
    for (int reg = 0; reg < 4; ++reg) {
      float mx = -1e30f, mn = 1e30f;
#pragma unroll
      for (int tn = 0; tn < 4; ++tn) {
        mx = fmaxf(mx, uk[tn][reg]);
        mn = fminf(mn, uk[tn][reg]);
      }
#pragma unroll
      for (int o = 1; o <= 8; o <<= 1) {
        mx = fmaxf(mx, __shfl_xor(mx, o, 64));
        mn = fminf(mn, __shfl_xor(mn, o, 64));
      }
      float ep[4], em[4], sp = 0.f, sm = 0.f;
#pragma unroll
      for (int tn = 0; tn < 4; ++tn) {
        ep[tn] = __expf(uk[tn][reg] - mx); sp += ep[tn];
        em[tn] = __expf(mn - uk[tn][reg]); sm += em[tn];
      }
#pragma unroll
      for (int o = 1; o <= 8; o <<= 1) {
        sp += __shfl_xor(sp, o, 64);
        sm += __shfl_xor(sm, o, 64);
      }
      const float rp = 1.f / sp, rm = 1.f / sm;
      const int srow = r0 + g * 4 + reg;
#pragma unroll
      for (int tn = 0; tn < 4; ++tn) {
        int f = tn * 16 + rl;
        lds_w16(phiT, f,      2 * S_, srow * 2, f2bf(ep[tn] * rp));
        lds_w16(phiT, f + 64, 2 * S_, srow * 2, f2bf(em[tn] * rm));
      }
    }

    // scores softmax -> Pl (wave-private, w folded)
#pragma unroll
    for (int reg = 0; reg < 4; ++reg) {
      float mx = -1e30f;
#pragma unroll
      for (int tn = 0; tn < 4; ++tn) {
        sacc[tn][reg] *= SCALING_;
        mx = fmaxf(mx, sacc[tn][reg]);
      }
#pragma unroll
      for (int o = 1; o <= 8; o <<= 1) mx = fmaxf(mx, __shfl_xor(mx, o, 64));
      float e_[4], sum = 0.f;
#pragma unroll
      for (int tn = 0; tn < 4; ++tn) {
        e_[tn] = __expf(sacc[tn][reg] - mx);
        sum += e_[tn];
      }
#pragma unroll
      for (int o = 1; o <= 8; o <<= 1) sum += __shfl_xor(sum, o, 64);
      const float pw = w / sum;
      const int srow = r0 + g * 4 + reg;
#pragma unroll
      for (int tn = 0; tn < 4; ++tn)
        lds_w16(Pl, srow, 2 * S_, (tn * 16 + rl) * 2, f2bf(e_[tn] * pw));
    }

    // out = (phi @ img) * cl + P @ V
    f32x4 ao[8];
#pragma unroll
    for (int tn = 0; tn < 8; ++tn) ao[tn] = z4;
#pragma unroll
    for (int ks = 0; ks < 4; ++ks) {
      s16x8 a = swz_frag(phi, r0 + rl, 2 * F2_, (ks * 32 + kl) * 2);
#pragma unroll
      for (int tn = 0; tn < 8; ++tn) {
        s16x8 b = swz_frag(img, tn * 16 + rl, 2 * F2_, (ks * 32 + kl) * 2);
        ao[tn] = MFMA(a, b, ao[tn]);
      }
    }
#pragma unroll
    for (int tn = 0; tn < 8; ++tn)
#pragma unroll
      for (int reg = 0; reg < 4; ++reg) ao[tn][reg] *= cl[reg];
#pragma unroll
    for (int ks = 0; ks < 2; ++ks) {
      s16x8 a = swz_frag(Pl, r0 + rl, 2 * S_, (ks * 32 + kl) * 2);
#pragma unroll
      for (int tn = 0; tn < 8; ++tn) {
        s16x8 b = swz_frag(VTb, tn * 16 + rl, 2 * S_, (ks * 32 + kl) * 2);
        ao[tn] = MFMA(a, b, ao[tn]);
      }
    }
    {
      float* Ob = Out + (size_t)blk * (S_ * D_);
#pragma unroll
      for (int tn = 0; tn < 8; ++tn)
#pragma unroll
        for (int reg = 0; reg < 4; ++reg) {
          int srow = r0 + g * 4 + reg;
          Ob[(size_t)srow * D_ + tn * 16 + rl] = ao[tn][reg];
        }
    }
    __syncthreads();   // phiT complete; all img/Zl reads done

    // state update: acc += VT(d-rows) @ phiT ; Zl += colsum(phi_k)
#pragma unroll
    for (int ks = 0; ks < 2; ++ks) {
      s16x8 a[2];
#pragma unroll
      for (int tm = 0; tm < 2; ++tm)
        a[tm] = swz_frag(VTb, wave * 32 + tm * 16 + rl, 2 * S_, (ks * 32 + kl) * 2);
#pragma unroll
      for (int tn = 0; tn < 8; ++tn) {
        s16x8 b = swz_frag(phiT, tn * 16 + rl, 2 * S_, (ks * 32 + kl) * 2);
#pragma unroll
        for (int tm = 0; tm < 2; ++tm)
          acc[tm][tn] = MFMA(a[tm], b, acc[tm][tn]);
      }
    }
    {
      const int f = tid >> 1, half = tid & 1;
      float z = 0.f;
#pragma unroll
      for (int j2 = 0; j2 < 4; ++j2) {
        s16x8 v = swz_frag(phiT, f, 2 * S_, (half * 32 + j2 * 8) * 2);
#pragma unroll
        for (int e = 0; e < 8; ++e) z += bf2f(v[e]);
      }
      z += __shfl_xor(z, 1, 64);
      if (half == 0) Zl[f] += z;
    }
    // next iteration's __syncthreads (after repack) publishes img + Zl
  }
}

// ---------------------------------------------------------------------------
extern "C" void kernel_launch(void* const* d_in, const int* in_sizes, int n_in,
                              void* d_out, int out_size, void* d_ws, size_t ws_size,
                              hipStream_t stream)
{
  const float* Q = (const float*)d_in[0];
  const float* K = (const float*)d_in[1];
  const float* V = (const float*)d_in[2];
  const float* W = (const float*)d_in[3];
  const float* alpha = (const float*)d_in[4];
  float* Out = (float*)d_out;

  char* ws = (char*)d_ws;
  short* VT = (short*)ws;                                    // 32 MiB
  f32x4* Sc4 = (f32x4*)(ws + (size_t)32 * 1024 * 1024);      // 32 MiB
  float* Zc = (float*)(ws + (size_t)64 * 1024 * 1024);       // 256 KiB
  short* Wt = (short*)(ws + (size_t)64 * 1024 * 1024 + 256 * 1024);  // 256 KiB

  hipLaunchKernelGGL(prep_w, dim3(H_), dim3(256), 0, stream, W, Wt);
  hipLaunchKernelGGL(bslh_chunksum, dim3(NCHT_), dim3(256), 0, stream,
                     K, V, Wt, VT, Sc4, Zc);
  hipLaunchKernelGGL(bslh_scanc, dim3(516), dim3(256), 0, stream,
                     Sc4, (f32x4*)Zc);
  hipLaunchKernelGGL(bslh_walk, dim3(NCHT_), dim3(256), 0, stream,
                     Q, K, VT, Wt, Sc4, Zc, alpha, Out);
}

// Round 14
// 197.276 us; speedup vs baseline: 1.6750x; 1.6750x over previous
//
#include <hip/hip_runtime.h>
#include <math.h>

// Problem constants (fixed by reference)
#define B_ 2
#define H_ 16
#define L_ 4096
#define D_ 128
#define F_ 64
#define F2_ 128
#define S_ 64
#define N_ 64
#define BH_ 32
#define NBT_ 2048
#define EPS_ 1e-6f
#define SCALING_ 0.08838834764831845f  // 128^-0.5

typedef float f32x4 __attribute__((ext_vector_type(4)));
typedef short s16x8 __attribute__((ext_vector_type(8)));
typedef short s16x4 __attribute__((ext_vector_type(4)));

#define MFMA(a, b, c) __builtin_amdgcn_mfma_f32_16x16x32_bf16(a, b, c, 0, 0, 0)

__device__ __forceinline__ short f2bf(float f) {
  unsigned u = __float_as_uint(f);
  u += 0x7fffu + ((u >> 16) & 1u);   // RNE
  return (short)(u >> 16);
}
__device__ __forceinline__ float bf2f(short s) {
  return __uint_as_float(((unsigned)(unsigned short)s) << 16);
}

// 8 consecutive fp32 -> bf16 fragment
__device__ __forceinline__ s16x8 frag_f32(const float* p) {
  f32x4 a = *(const f32x4*)p;
  f32x4 b = *(const f32x4*)(p + 4);
  s16x8 r;
  r[0] = f2bf(a[0]); r[1] = f2bf(a[1]); r[2] = f2bf(a[2]); r[3] = f2bf(a[3]);
  r[4] = f2bf(b[0]); r[5] = f2bf(b[1]); r[6] = f2bf(b[2]); r[7] = f2bf(b[3]);
  return r;
}

// XOR swizzle: byte ^= (row&7)<<4 within a row. Used for LDS bank-conflict
// avoidance AND baked into the St/VT global layouts.
__device__ __forceinline__ s16x8 swz_frag(const short* base, int row, int rowBytes, int colByte) {
  int byte = row * rowBytes + (colByte ^ ((row & 7) << 4));
  return *(const s16x8*)((const char*)base + byte);
}
__device__ __forceinline__ void lds_w16(short* lds, int row, int rowBytes, int colByte, short v) {
  int byte = row * rowBytes + (colByte ^ ((row & 7) << 4));
  *(short*)((char*)lds + byte) = v;
}

// ---------------------------------------------------------------------------
// prep_w: Wt[h][f][d] bf16 (transposed) so B-fragments of u=x@W are contiguous.
// ---------------------------------------------------------------------------
__global__ __launch_bounds__(256)
void prep_w(const float* __restrict__ W, short* __restrict__ Wt)
{
  const int h = blockIdx.x;
  const int tid = threadIdx.x;
  const int f = tid & 63, gq = tid >> 6;
  const float* Wh = W + (size_t)h * D_ * F_;
  short* Wo = Wt + (size_t)h * F_ * D_ + (size_t)f * D_ + gq * 32;
  short buf[32];
#pragma unroll
  for (int j = 0; j < 32; ++j) buf[j] = f2bf(Wh[(size_t)(gq * 32 + j) * F_ + f]);
#pragma unroll
  for (int j2 = 0; j2 < 4; ++j2) {
    s16x8 v;
#pragma unroll
    for (int e = 0; e < 8; ++e) v[e] = buf[j2 * 8 + e];
    *(s16x8*)(Wo + j2 * 8) = v;
  }
}

// ---------------------------------------------------------------------------
// phase1 (R7): stage V -> VTs LDS image (transpose + bf16, baked swizzle);
// u = k@W (MFMA); phi_k -> phiT (LDS, swizzled); dZ colsums; dSt (MFMA);
// coalesced VT + St global writes.
// ---------------------------------------------------------------------------
__global__ __launch_bounds__(256, 3)
void bslh_phase1(const float* __restrict__ K, const float* __restrict__ V,
                 const short* __restrict__ Wt, short* __restrict__ VT,
                 short* __restrict__ dSt, float* __restrict__ dZ)
{
  __shared__ __align__(16) char lds[32 * 1024];
  short* phiT = (short*)lds;              // 16KB [128 f][128B] swizzled
  short* VTs = (short*)(lds + 16384);     // 16KB [128 d][128B] baked layout

  const int blk = blockIdx.x;
  const int bh = blk / N_;
  const int h = bh % H_;
  const int tid = threadIdx.x;
  const int wave = tid >> 6, lane = tid & 63;
  const int rl = lane & 15, g = lane >> 4, kl = g * 8;
  const int r0 = wave * 16;

  // ---- stage V -> VTs (transpose + bf16) ----
  {
    const float4* gv = (const float4*)(V + (size_t)blk * S_ * D_);
#pragma unroll
    for (int ii = 0; ii < 8; ++ii) {
      int idx = tid + 256 * ii;
      int s = idx >> 5, c = (idx & 31) * 4;
      float4 v = gv[idx];
      float o0 = __shfl_xor(v.x, 32, 64);
      float o1 = __shfl_xor(v.y, 32, 64);
      float o2 = __shfl_xor(v.z, 32, 64);
      float o3 = __shfl_xor(v.w, 32, 64);
      if (!(tid & 32)) {
        float m[4] = {v.x, v.y, v.z, v.w};
        float o[4] = {o0, o1, o2, o3};
#pragma unroll
        for (int j = 0; j < 4; ++j) {
          int d = c + j;
          unsigned pk = (unsigned)(unsigned short)f2bf(m[j]) |
                        ((unsigned)(unsigned short)f2bf(o[j]) << 16);
          int byte = d * 128 + ((s * 2) ^ ((d & 7) << 4));
          *(unsigned*)((char*)VTs + byte) = pk;
        }
      }
    }
  }

  const float* Kb = K + (size_t)blk * (S_ * D_);
  const short* Wh = Wt + (size_t)h * (F_ * D_);
  const f32x4 z4 = {0.f, 0.f, 0.f, 0.f};

  // ---- u = k @ W ----
  f32x4 uacc[4] = {z4, z4, z4, z4};
  for (int ks = 0; ks < 4; ++ks) {
    s16x8 a = frag_f32(Kb + (size_t)(r0 + rl) * D_ + ks * 32 + kl);
#pragma unroll
    for (int tn = 0; tn < 4; ++tn) {
      s16x8 b = *(const s16x8*)(Wh + (size_t)(tn * 16 + rl) * D_ + ks * 32 + kl);
      uacc[tn] = MFMA(a, b, uacc[tn]);
    }
  }

  // ---- phi = [softmax(u), softmax(-u)] -> phiT (transposed, swizzled) ----
#pragma unroll
  for (int reg = 0; reg < 4; ++reg) {
    float mx = -1e30f, mn = 1e30f;
#pragma unroll
    for (int tn = 0; tn < 4; ++tn) {
      mx = fmaxf(mx, uacc[tn][reg]);
      mn = fminf(mn, uacc[tn][reg]);
    }
#pragma unroll
    for (int o = 1; o <= 8; o <<= 1) {
      mx = fmaxf(mx, __shfl_xor(mx, o, 64));
      mn = fminf(mn, __shfl_xor(mn, o, 64));
    }
    float ep[4], em[4], sp = 0.f, sm = 0.f;
#pragma unroll
    for (int tn = 0; tn < 4; ++tn) {
      ep[tn] = __expf(uacc[tn][reg] - mx); sp += ep[tn];
      em[tn] = __expf(mn - uacc[tn][reg]); sm += em[tn];
    }
#pragma unroll
    for (int o = 1; o <= 8; o <<= 1) {
      sp += __shfl_xor(sp, o, 64);
      sm += __shfl_xor(sm, o, 64);
    }
    const float rp = 1.f / sp, rm = 1.f / sm;
    const int srow = r0 + g * 4 + reg;
#pragma unroll
    for (int tn = 0; tn < 4; ++tn) {
      int f = tn * 16 + rl;
      lds_w16(phiT, f,      2 * S_, srow * 2, f2bf(ep[tn] * rp));
      lds_w16(phiT, f + 64, 2 * S_, srow * 2, f2bf(em[tn] * rm));
    }
  }
  __syncthreads();   // phiT + VTs images complete (cross-wave consumers below)

  // ---- write VT global (coalesced float4 copy of the 16KB image) ----
  {
    float4* dst = (float4*)(VT + (size_t)blk * (D_ * S_));
    const float4* src = (const float4*)VTs;
#pragma unroll
    for (int i = 0; i < 4; ++i) dst[tid + 256 * i] = src[tid + 256 * i];
  }

  // ---- dZ[f] = sum_s phi[s][f] ----
  {
    const int f = tid >> 1, half = tid & 1;
    float z = 0.f;
#pragma unroll
    for (int j2 = 0; j2 < 4; ++j2) {
      s16x8 v = swz_frag(phiT, f, 2 * S_, (half * 32 + j2 * 8) * 2);
#pragma unroll
      for (int e = 0; e < 8; ++e) z += bf2f(v[e]);
    }
    z += __shfl_xor(z, 1, 64);
    if (half == 0) dZ[(size_t)blk * F2_ + f] = z;
  }

  // ---- dSt[d][f] = sum_s v[s][d]*phi[s][f]; wave owns d-rows 32w..32w+31 ----
  f32x4 acc[2][8];
#pragma unroll
  for (int tm = 0; tm < 2; ++tm)
#pragma unroll
    for (int tn = 0; tn < 8; ++tn) acc[tm][tn] = z4;

  for (int ks = 0; ks < 2; ++ks) {
    s16x8 a[2];
#pragma unroll
    for (int tm = 0; tm < 2; ++tm)
      a[tm] = swz_frag(VTs, wave * 32 + tm * 16 + rl, 2 * S_, (ks * 32 + kl) * 2);
#pragma unroll
    for (int tn = 0; tn < 8; ++tn) {
      s16x8 b = swz_frag(phiT, tn * 16 + rl, 2 * S_, (ks * 32 + kl) * 2);
#pragma unroll
      for (int tm = 0; tm < 2; ++tm)
        acc[tm][tn] = MFMA(a[tm], b, acc[tm][tn]);
    }
  }
  __syncthreads();   // all phiT/VTs reads done; reuse lds as St image

  // ---- pack acc into LDS St image (baked swizzle), coalesced store ----
  short* Stb = (short*)lds;
#pragma unroll
  for (int tm = 0; tm < 2; ++tm)
#pragma unroll
    for (int tn = 0; tn < 8; ++tn)
#pragma unroll
      for (int reg = 0; reg < 4; ++reg) {
        float v0 = acc[tm][tn][reg];
        float v1 = __shfl_xor(v0, 1, 64);
        if (!(lane & 1)) {
          int drow = wave * 32 + tm * 16 + g * 4 + reg;
          int fcol = tn * 16 + rl;
          unsigned pk = (unsigned)(unsigned short)f2bf(v0) |
                        ((unsigned)(unsigned short)f2bf(v1) << 16);
          int byte = drow * 256 + ((fcol * 2) ^ ((drow & 7) << 4));
          *(unsigned*)((char*)Stb + byte) = pk;
        }
      }
  __syncthreads();

  float4* dst = (float4*)(dSt + (size_t)blk * (F2_ * D_));
  const float4* srcl = (const float4*)lds;
#pragma unroll
  for (int i = 0; i < 8; ++i) dst[tid + 256 * i] = srcl[tid + 256 * i];
}

// ---------------------------------------------------------------------------
// scan: blocks [0,512) -> exclusive prefix of St in 4-short chunks
// (XOR permutes 16B units; 8B sub-units are layout-agnostic);
// blocks [512,516) -> exclusive prefix of dZ (fp32). unroll 8 for load ILP.
// ---------------------------------------------------------------------------
__global__ __launch_bounds__(256)
void bslh_scan(short* __restrict__ St, float4* __restrict__ dZ4)
{
  const int tid = threadIdx.x;
  if (blockIdx.x < 512) {
    const int idx = blockIdx.x * 256 + tid;      // 131072 threads
    const int bh = idx >> 12;
    const int rem = idx & 4095;
    short* p = St + (size_t)bh * N_ * (F2_ * D_) + (size_t)rem * 4;
    float run[4] = {0.f, 0.f, 0.f, 0.f};
#pragma unroll 8
    for (int n = 0; n < N_; ++n) {
      s16x4 v = *(const s16x4*)p;
      s16x4 o;
#pragma unroll
      for (int e = 0; e < 4; ++e) {
        o[e] = f2bf(run[e]);
        run[e] += bf2f(v[e]);
      }
      *(s16x4*)p = o;
      p += F2_ * D_;
    }
  } else {
    const int idx = (blockIdx.x - 512) * 256 + tid;  // 1024 threads
    const int bh = idx >> 5, e = idx & 31;
    float4* p = dZ4 + (size_t)bh * N_ * 32 + e;
    float4 run = make_float4(0.f, 0.f, 0.f, 0.f);
#pragma unroll 8
    for (int n = 0; n < N_; ++n) {
      float4 v = p[(size_t)n * 32];
      p[(size_t)n * 32] = run;
      run.x += v.x; run.y += v.y; run.z += v.z; run.w += v.w;
    }
  }
}

// ---------------------------------------------------------------------------
// phase3 (R7 structure; launch_bounds raised 4->6 for residency):
// u=q@W -> phi_q (LDS); cl=(1-w)/max(phi·Z,eps); scores (Q A-frags reused)
// -> P*w (LDS); acc = (phi @ St)*cl + P @ V; store.
// ---------------------------------------------------------------------------
__global__ __launch_bounds__(256, 6)
void bslh_phase3(const float* __restrict__ Q, const float* __restrict__ K,
                 const short* __restrict__ VT, const short* __restrict__ Wt,
                 const short* __restrict__ St, const float* __restrict__ Zp,
                 const float* __restrict__ alphap, float* __restrict__ Out)
{
  __shared__ __align__(16) short phi[S_ * F2_];  // 16KB [64][256B] swizzled
  __shared__ __align__(16) short Pl[S_ * S_];    // 8KB  [64][128B] swizzled
  __shared__ float clL[S_];

  const int blk = blockIdx.x;
  const int bh = blk / N_;
  const int h = bh % H_;
  const int tid = threadIdx.x;
  const int wave = tid >> 6, lane = tid & 63;
  const int rl = lane & 15, g = lane >> 4, kl = g * 8;
  const int r0 = wave * 16;

  const short* Sb = St + (size_t)blk * (F2_ * D_);
  const short* VTb = VT + (size_t)blk * (D_ * S_);
  const float* Qb = Q + (size_t)blk * (S_ * D_);
  const float* Kb = K + (size_t)blk * (S_ * D_);
  const short* Wh = Wt + (size_t)h * (F_ * D_);
  const float w = 1.f / (1.f + __expf(-alphap[0]));
  const f32x4 z4 = {0.f, 0.f, 0.f, 0.f};

  // ---- u = q @ W (save Q A-fragments for scores) ----
  s16x8 aq[4];
  f32x4 uacc[4] = {z4, z4, z4, z4};
  for (int ks = 0; ks < 4; ++ks) {
    aq[ks] = frag_f32(Qb + (size_t)(r0 + rl) * D_ + ks * 32 + kl);
#pragma unroll
    for (int tn = 0; tn < 4; ++tn) {
      s16x8 b = *(const s16x8*)(Wh + (size_t)(tn * 16 + rl) * D_ + ks * 32 + kl);
      uacc[tn] = MFMA(aq[ks], b, uacc[tn]);
    }
  }

  // ---- phi_q (row-major, swizzled) ----
#pragma unroll
  for (int reg = 0; reg < 4; ++reg) {
    float mx = -1e30f, mn = 1e30f;
#pragma unroll
    for (int tn = 0; tn < 4; ++tn) {
      mx = fmaxf(mx, uacc[tn][reg]);
      mn = fminf(mn, uacc[tn][reg]);
    }
#pragma unroll
    for (int o = 1; o <= 8; o <<= 1) {
      mx = fmaxf(mx, __shfl_xor(mx, o, 64));
      mn = fminf(mn, __shfl_xor(mn, o, 64));
    }
    float ep[4], em[4], sp = 0.f, sm = 0.f;
#pragma unroll
    for (int tn = 0; tn < 4; ++tn) {
      ep[tn] = __expf(uacc[tn][reg] - mx); sp += ep[tn];
      em[tn] = __expf(mn - uacc[tn][reg]); sm += em[tn];
    }
#pragma unroll
    for (int o = 1; o <= 8; o <<= 1) {
      sp += __shfl_xor(sp, o, 64);
      sm += __shfl_xor(sm, o, 64);
    }
    const float rp = 1.f / sp, rm = 1.f / sm;
    const int srow = r0 + g * 4 + reg;
#pragma unroll
    for (int tn = 0; tn < 4; ++tn) {
      int f = tn * 16 + rl;
      lds_w16(phi, srow, 2 * F2_, f * 2,        f2bf(ep[tn] * rp));
      lds_w16(phi, srow, 2 * F2_, (f + 64) * 2, f2bf(em[tn] * rm));
    }
  }
  __syncthreads();

  // ---- cl[row] = (1-w)/max(phi·Zprefix, eps) ----
  if (tid < 64) {
    const float* Zb = Zp + (size_t)blk * F2_;
    float den = 0.f;
#pragma unroll
    for (int j2 = 0; j2 < 16; ++j2) {
      s16x8 v = swz_frag(phi, tid, 2 * F2_, j2 * 16);
      f32x4 z0 = *(const f32x4*)(Zb + j2 * 8);
      f32x4 z1 = *(const f32x4*)(Zb + j2 * 8 + 4);
      den += bf2f(v[0]) * z0[0] + bf2f(v[1]) * z0[1] +
             bf2f(v[2]) * z0[2] + bf2f(v[3]) * z0[3] +
             bf2f(v[4]) * z1[0] + bf2f(v[5]) * z1[1] +
             bf2f(v[6]) * z1[2] + bf2f(v[7]) * z1[3];
    }
    clL[tid] = (1.f - w) / fmaxf(den, EPS_);
  }

  // ---- scores = q @ k^T (A-frags reused), softmax, P*w -> Pl ----
  f32x4 sacc[4] = {z4, z4, z4, z4};
  for (int ks = 0; ks < 4; ++ks) {
#pragma unroll
    for (int tn = 0; tn < 4; ++tn) {
      s16x8 b = frag_f32(Kb + (size_t)(tn * 16 + rl) * D_ + ks * 32 + kl);
      sacc[tn] = MFMA(aq[ks], b, sacc[tn]);
    }
  }
#pragma unroll
  for (int reg = 0; reg < 4; ++reg) {
    float mx = -1e30f;
#pragma unroll
    for (int tn = 0; tn < 4; ++tn) {
      sacc[tn][reg] *= SCALING_;
      mx = fmaxf(mx, sacc[tn][reg]);
    }
#pragma unroll
    for (int o = 1; o <= 8; o <<= 1) mx = fmaxf(mx, __shfl_xor(mx, o, 64));
    float e_[4], sum = 0.f;
#pragma unroll
    for (int tn = 0; tn < 4; ++tn) {
      e_[tn] = __expf(sacc[tn][reg] - mx);
      sum += e_[tn];
    }
#pragma unroll
    for (int o = 1; o <= 8; o <<= 1) sum += __shfl_xor(sum, o, 64);
    const float pw = w / sum;
    const int srow = r0 + g * 4 + reg;
#pragma unroll
    for (int tn = 0; tn < 4; ++tn)
      lds_w16(Pl, srow, 2 * S_, (tn * 16 + rl) * 2, f2bf(e_[tn] * pw));
  }
  __syncthreads();

  // ---- acc = phi @ St (St direct from global, baked swizzle), *cl ----
  f32x4 acc[8];
#pragma unroll
  for (int tn = 0; tn < 8; ++tn) acc[tn] = z4;

  for (int ks = 0; ks < 4; ++ks) {
    s16x8 a = swz_frag(phi, r0 + rl, 2 * F2_, (ks * 32 + kl) * 2);
#pragma unroll
    for (int tn = 0; tn < 8; ++tn) {
      s16x8 b = swz_frag(Sb, tn * 16 + rl, 2 * F2_, (ks * 32 + kl) * 2);
      acc[tn] = MFMA(a, b, acc[tn]);
    }
  }
  float cl[4];
#pragma unroll
  for (int reg = 0; reg < 4; ++reg) cl[reg] = clL[r0 + g * 4 + reg];
#pragma unroll
  for (int tn = 0; tn < 8; ++tn)
#pragma unroll
    for (int reg = 0; reg < 4; ++reg) acc[tn][reg] *= cl[reg];

  // ---- acc += P @ V (VT direct from global, baked swizzle) ----
  for (int ks = 0; ks < 2; ++ks) {
    s16x8 a = swz_frag(Pl, r0 + rl, 2 * S_, (ks * 32 + kl) * 2);
#pragma unroll
    for (int tn = 0; tn < 8; ++tn) {
      s16x8 b = swz_frag(VTb, tn * 16 + rl, 2 * S_, (ks * 32 + kl) * 2);
      acc[tn] = MFMA(a, b, acc[tn]);
    }
  }

  // ---- store ----
  float* Ob = Out + (size_t)blk * (S_ * D_);
#pragma unroll
  for (int tn = 0; tn < 8; ++tn)
#pragma unroll
    for (int reg = 0; reg < 4; ++reg) {
      int srow = r0 + g * 4 + reg;
      Ob[(size_t)srow * D_ + tn * 16 + rl] = acc[tn][reg];
    }
}

// ---------------------------------------------------------------------------
extern "C" void kernel_launch(void* const* d_in, const int* in_sizes, int n_in,
                              void* d_out, int out_size, void* d_ws, size_t ws_size,
                              hipStream_t stream)
{
  const float* Q = (const float*)d_in[0];
  const float* K = (const float*)d_in[1];
  const float* V = (const float*)d_in[2];
  const float* W = (const float*)d_in[3];
  const float* alpha = (const float*)d_in[4];
  float* Out = (float*)d_out;

  short* VT = (short*)d_ws;                              // 32 MiB
  short* St = VT + (size_t)NBT_ * D_ * S_;               // 64 MiB
  float* dZ = (float*)(St + (size_t)NBT_ * F2_ * D_);    // 1 MiB
  short* Wt = (short*)(dZ + (size_t)NBT_ * F2_);         // 256 KiB

  hipLaunchKernelGGL(prep_w, dim3(H_), dim3(256), 0, stream, W, Wt);
  hipLaunchKernelGGL(bslh_phase1, dim3(NBT_), dim3(256), 0, stream,
                     K, V, Wt, VT, St, dZ);
  hipLaunchKernelGGL(bslh_scan, dim3(516), dim3(256), 0, stream, St, (float4*)dZ);
  hipLaunchKernelGGL(bslh_phase3, dim3(NBT_), dim3(256), 0, stream,
                     Q, K, VT, Wt, St, dZ, alpha, Out);
}

// Round 15
// 139.515 us; speedup vs baseline: 2.3685x; 1.4140x over previous
//
#include <hip/hip_runtime.h>
#include <math.h>

// Problem constants (fixed by reference)
#define B_ 2
#define H_ 16
#define L_ 4096
#define D_ 128
#define F_ 64
#define F2_ 128
#define S_ 64
#define N_ 64
#define BH_ 32
#define NBT_ 2048
#define EPS_ 1e-6f
#define SCALING_ 0.08838834764831845f  // 128^-0.5

typedef float f32x4 __attribute__((ext_vector_type(4)));
typedef short s16x8 __attribute__((ext_vector_type(8)));
typedef short s16x4 __attribute__((ext_vector_type(4)));

#define MFMA(a, b, c) __builtin_amdgcn_mfma_f32_16x16x32_bf16(a, b, c, 0, 0, 0)

// Fragment-major layout: per 64-token block, MFMA B/A fragments stored as
// contiguous 1KB units: unit (tn,ks), lane l=(g<<4)|rl holds 16B at l*16.
// Content: X[tn*16 + (l&15)][ks*32 + (l>>4)*8 + e], e=0..7 (bf16).

__device__ __forceinline__ short f2bf(float f) {
  unsigned u = __float_as_uint(f);
  u += 0x7fffu + ((u >> 16) & 1u);   // RNE
  return (short)(u >> 16);
}
__device__ __forceinline__ float bf2f(short s) {
  return __uint_as_float(((unsigned)(unsigned short)s) << 16);
}
__device__ __forceinline__ s16x8 pack8(f32x4 a, f32x4 b) {
  s16x8 r;
  r[0] = f2bf(a[0]); r[1] = f2bf(a[1]); r[2] = f2bf(a[2]); r[3] = f2bf(a[3]);
  r[4] = f2bf(b[0]); r[5] = f2bf(b[1]); r[6] = f2bf(b[2]); r[7] = f2bf(b[3]);
  return r;
}
__device__ __forceinline__ s16x8 frag_f32(const float* p) {
  f32x4 a = *(const f32x4*)p;
  f32x4 b = *(const f32x4*)(p + 4);
  return pack8(a, b);
}

// XOR swizzle for LDS images: byte ^= (row&7)<<4 within a row.
__device__ __forceinline__ s16x8 swz_frag(const short* base, int row, int rowBytes, int colByte) {
  int byte = row * rowBytes + (colByte ^ ((row & 7) << 4));
  return *(const s16x8*)((const char*)base + byte);
}
__device__ __forceinline__ void lds_w16(short* lds, int row, int rowBytes, int colByte, short v) {
  int byte = row * rowBytes + (colByte ^ ((row & 7) << 4));
  *(short*)((char*)lds + byte) = v;
}

// ---------------------------------------------------------------------------
// prep_w: Wfm[h] fragment-major (16 KB per h).
// ---------------------------------------------------------------------------
__global__ __launch_bounds__(256)
void prep_w(const float* __restrict__ W, short* __restrict__ Wfm)
{
  const int h = blockIdx.x;
  const int tid = threadIdx.x;
  const int f = tid & 63, gq = tid >> 6;   // gq = ks (d-chunk of 32)
  const float* Wh = W + (size_t)h * D_ * F_;
  short buf[32];
#pragma unroll
  for (int j = 0; j < 32; ++j) buf[j] = f2bf(Wh[(size_t)(gq * 32 + j) * F_ + f]);
  short* Wo = Wfm + (size_t)h * 8192 + ((((f >> 4) * 4 + gq)) << 9);
#pragma unroll
  for (int gp = 0; gp < 4; ++gp) {
    s16x8 v;
#pragma unroll
    for (int e = 0; e < 8; ++e) v[e] = buf[gp * 8 + e];
    *(s16x8*)(Wo + ((gp << 4) + (f & 15)) * 8) = v;
  }
}

// ---------------------------------------------------------------------------
// phase1: V->VTs image; u=k@W (Wfm dense reads); Kfm export (direct from
// registers, coalesced); phi_k -> phiT; dZ (bf16); dSt MFMA; Vfm + Sfm
// exports in fragment-major layout (coalesced writes).
// ---------------------------------------------------------------------------
__global__ __launch_bounds__(256, 3)
void bslh_phase1(const float* __restrict__ K, const float* __restrict__ V,
                 const short* __restrict__ Wfm, short* __restrict__ Vfm,
                 short* __restrict__ Kfm, short* __restrict__ Sfm,
                 short* __restrict__ dZ)
{
  __shared__ __align__(16) char lds[32 * 1024];
  short* phiT = (short*)lds;              // 16KB [128 f][128B] swizzled
  short* VTs = (short*)(lds + 16384);     // 16KB [128 d][128B] swizzled

  const int blk = blockIdx.x;
  const int bh = blk / N_;
  const int h = bh % H_;
  const int tid = threadIdx.x;
  const int wave = tid >> 6, lane = tid & 63;
  const int rl = lane & 15, g = lane >> 4, kl = g * 8;
  const int r0 = wave * 16;

  const float* Kb = K + (size_t)blk * (S_ * D_);
  const short* Wh = Wfm + (size_t)h * 8192;
  const f32x4 z4 = {0.f, 0.f, 0.f, 0.f};

  // ---- batch-issue V + K loads ----
  f32x4 vv[8];
  {
    const f32x4* gv = (const f32x4*)(V + (size_t)blk * S_ * D_);
#pragma unroll
    for (int ii = 0; ii < 8; ++ii) vv[ii] = gv[tid + 256 * ii];
  }
  f32x4 kv[8];
  {
    const float* kp = Kb + (size_t)(r0 + rl) * D_ + kl;
#pragma unroll
    for (int i = 0; i < 8; ++i) kv[i] = *(const f32x4*)(kp + (i >> 1) * 32 + (i & 1) * 4);
  }

  // ---- V transpose -> VTs image ----
#pragma unroll
  for (int ii = 0; ii < 8; ++ii) {
    int idx = tid + 256 * ii;
    int s = idx >> 5, c = (idx & 31) * 4;
    float m0 = vv[ii][0], m1 = vv[ii][1], m2 = vv[ii][2], m3 = vv[ii][3];
    float o0 = __shfl_xor(m0, 32, 64);
    float o1 = __shfl_xor(m1, 32, 64);
    float o2 = __shfl_xor(m2, 32, 64);
    float o3 = __shfl_xor(m3, 32, 64);
    if (!(tid & 32)) {
      float m[4] = {m0, m1, m2, m3};
      float o[4] = {o0, o1, o2, o3};
#pragma unroll
      for (int j = 0; j < 4; ++j) {
        int d = c + j;
        unsigned pk = (unsigned)(unsigned short)f2bf(m[j]) |
                      ((unsigned)(unsigned short)f2bf(o[j]) << 16);
        int byte = d * 128 + ((s * 2) ^ ((d & 7) << 4));
        *(unsigned*)((char*)VTs + byte) = pk;
      }
    }
  }

  // ---- K fragments + Kfm export (coalesced 1KB stores) ----
  s16x8 aq[4];
#pragma unroll
  for (int ks = 0; ks < 4; ++ks) aq[ks] = pack8(kv[2 * ks], kv[2 * ks + 1]);
  {
    short* Ko = Kfm + (size_t)blk * 8192;
#pragma unroll
    for (int ks = 0; ks < 4; ++ks)
      *(s16x8*)(Ko + (((wave * 4 + ks)) << 9) + lane * 8) = aq[ks];
  }

  // ---- u = k @ W (dense Wfm reads) ----
  f32x4 uacc[4] = {z4, z4, z4, z4};
#pragma unroll
  for (int ks = 0; ks < 4; ++ks) {
#pragma unroll
    for (int tn = 0; tn < 4; ++tn) {
      s16x8 b = *(const s16x8*)(Wh + (((tn * 4 + ks)) << 9) + lane * 8);
      uacc[tn] = MFMA(aq[ks], b, uacc[tn]);
    }
  }

  // ---- phi_k = [softmax(u), softmax(-u)] -> phiT ----
#pragma unroll
  for (int reg = 0; reg < 4; ++reg) {
    float mx = -1e30f, mn = 1e30f;
#pragma unroll
    for (int tn = 0; tn < 4; ++tn) {
      mx = fmaxf(mx, uacc[tn][reg]);
      mn = fminf(mn, uacc[tn][reg]);
    }
#pragma unroll
    for (int o = 1; o <= 8; o <<= 1) {
      mx = fmaxf(mx, __shfl_xor(mx, o, 64));
      mn = fminf(mn, __shfl_xor(mn, o, 64));
    }
    float ep[4], em[4], sp = 0.f, sm = 0.f;
#pragma unroll
    for (int tn = 0; tn < 4; ++tn) {
      ep[tn] = __expf(uacc[tn][reg] - mx); sp += ep[tn];
      em[tn] = __expf(mn - uacc[tn][reg]); sm += em[tn];
    }
#pragma unroll
    for (int o = 1; o <= 8; o <<= 1) {
      sp += __shfl_xor(sp, o, 64);
      sm += __shfl_xor(sm, o, 64);
    }
    const float rp = 1.f / sp, rm = 1.f / sm;
    const int srow = r0 + g * 4 + reg;
#pragma unroll
    for (int tn = 0; tn < 4; ++tn) {
      int f = tn * 16 + rl;
      lds_w16(phiT, f,      2 * S_, srow * 2, f2bf(ep[tn] * rp));
      lds_w16(phiT, f + 64, 2 * S_, srow * 2, f2bf(em[tn] * rm));
    }
  }
  __syncthreads();   // phiT + VTs complete

  // ---- Vfm export from VTs image (coalesced) ----
  {
    short* Vo = Vfm + (size_t)blk * 8192;
#pragma unroll
    for (int i = 0; i < 4; ++i) {
      int unit = i * 256 + tid;
      int l = unit & 63, ks = (unit >> 6) & 1, tn = unit >> 7;
      int d = tn * 16 + (l & 15);
      int sb = (ks * 32 + (l >> 4) * 8) * 2;
      s16x8 v = *(const s16x8*)((const char*)VTs + d * 128 + (sb ^ ((d & 7) << 4)));
      *(s16x8*)(Vo + unit * 8) = v;
    }
  }

  // ---- dZ[f] = colsum(phi_k) (bf16) ----
  {
    const int f = tid >> 1, half = tid & 1;
    float z = 0.f;
#pragma unroll
    for (int j2 = 0; j2 < 4; ++j2) {
      s16x8 v = swz_frag(phiT, f, 2 * S_, (half * 32 + j2 * 8) * 2);
#pragma unroll
      for (int e = 0; e < 8; ++e) z += bf2f(v[e]);
    }
    z += __shfl_xor(z, 1, 64);
    if (half == 0) dZ[(size_t)blk * F2_ + f] = f2bf(z);
  }

  // ---- dSt[d][f] MFMA; wave owns d-rows 32w..32w+31 ----
  f32x4 acc[2][8];
#pragma unroll
  for (int tm = 0; tm < 2; ++tm)
#pragma unroll
    for (int tn = 0; tn < 8; ++tn) acc[tm][tn] = z4;

#pragma unroll
  for (int ks = 0; ks < 2; ++ks) {
    s16x8 a[2];
#pragma unroll
    for (int tm = 0; tm < 2; ++tm)
      a[tm] = swz_frag(VTs, wave * 32 + tm * 16 + rl, 2 * S_, (ks * 32 + kl) * 2);
#pragma unroll
    for (int tn = 0; tn < 8; ++tn) {
      s16x8 b = swz_frag(phiT, tn * 16 + rl, 2 * S_, (ks * 32 + kl) * 2);
#pragma unroll
      for (int tm = 0; tm < 2; ++tm)
        acc[tm][tn] = MFMA(a[tm], b, acc[tm][tn]);
    }
  }
  __syncthreads();   // reuse lds as St image

  // ---- pack acc into St image [d-row 256B][f-col], swizzled ----
  short* Stb = (short*)lds;
#pragma unroll
  for (int tm = 0; tm < 2; ++tm)
#pragma unroll
    for (int tn = 0; tn < 8; ++tn)
#pragma unroll
      for (int reg = 0; reg < 4; ++reg) {
        float v0 = acc[tm][tn][reg];
        float v1 = __shfl_xor(v0, 1, 64);
        if (!(lane & 1)) {
          int drow = wave * 32 + tm * 16 + g * 4 + reg;
          int fcol = tn * 16 + rl;
          unsigned pk = (unsigned)(unsigned short)f2bf(v0) |
                        ((unsigned)(unsigned short)f2bf(v1) << 16);
          int byte = drow * 256 + ((fcol * 2) ^ ((drow & 7) << 4));
          *(unsigned*)((char*)Stb + byte) = pk;
        }
      }
  __syncthreads();

  // ---- Sfm export from St image (coalesced) ----
  {
    short* So = Sfm + (size_t)blk * 16384;
#pragma unroll
    for (int i = 0; i < 8; ++i) {
      int unit = i * 256 + tid;
      int l = unit & 63, ks = (unit >> 6) & 3, tn = unit >> 8;
      int d = tn * 16 + (l & 15);
      int fb = (ks * 32 + (l >> 4) * 8) * 2;
      s16x8 v = *(const s16x8*)((const char*)Stb + d * 256 + (fb ^ ((d & 7) << 4)));
      *(s16x8*)(So + unit * 8) = v;
    }
  }
}

// ---------------------------------------------------------------------------
// scan: blocks [0,512) -> exclusive prefix of Sfm in 4-short chunks
// (fragment-major is position-stable across n -> layout-agnostic);
// blocks [512,516) -> exclusive prefix of dZ (bf16).
// ---------------------------------------------------------------------------
__global__ __launch_bounds__(256)
void bslh_scan(short* __restrict__ St, short* __restrict__ dZ)
{
  const int tid = threadIdx.x;
  if (blockIdx.x < 512) {
    const int idx = blockIdx.x * 256 + tid;      // 131072 threads
    const int bh = idx >> 12;
    const int rem = idx & 4095;
    short* p = St + (size_t)bh * N_ * (F2_ * D_) + (size_t)rem * 4;
    float run[4] = {0.f, 0.f, 0.f, 0.f};
    for (int n = 0; n < N_; ++n) {
      s16x4 v = *(const s16x4*)p;
      s16x4 o;
#pragma unroll
      for (int e = 0; e < 4; ++e) {
        o[e] = f2bf(run[e]);
        run[e] += bf2f(v[e]);
      }
      *(s16x4*)p = o;
      p += F2_ * D_;
    }
  } else {
    const int idx = (blockIdx.x - 512) * 256 + tid;  // 1024 threads
    const int bh = idx >> 5, e = idx & 31;
    short* p = dZ + (size_t)bh * N_ * F2_ + (size_t)e * 4;
    float run[4] = {0.f, 0.f, 0.f, 0.f};
    for (int n = 0; n < N_; ++n) {
      s16x4 v = *(const s16x4*)p;
      s16x4 o;
#pragma unroll
      for (int e2 = 0; e2 < 4; ++e2) {
        o[e2] = f2bf(run[e2]);
        run[e2] += bf2f(v[e2]);
      }
      *(s16x4*)p = o;
      p += F2_;
    }
  }
}

// ---------------------------------------------------------------------------
// phase3 (R7 structure; ALL B-fragment loads fragment-major = contiguous
// 1KB per wave-load): u=q@W; phi_q; cl; scores (Kfm); P; lin (Sfm); PV (Vfm).
// ---------------------------------------------------------------------------
__global__ __launch_bounds__(256, 4)
void bslh_phase3(const float* __restrict__ Q, const short* __restrict__ Kfm,
                 const short* __restrict__ Vfm, const short* __restrict__ Wfm,
                 const short* __restrict__ Sfm, const short* __restrict__ Zp,
                 const float* __restrict__ alphap, float* __restrict__ Out)
{
  __shared__ __align__(16) short phi[S_ * F2_];  // 16KB [64][256B] swizzled
  __shared__ __align__(16) short Pl[S_ * S_];    // 8KB  [64][128B] swizzled
  __shared__ float clL[S_];

  const int blk = blockIdx.x;
  const int bh = blk / N_;
  const int h = bh % H_;
  const int tid = threadIdx.x;
  const int wave = tid >> 6, lane = tid & 63;
  const int rl = lane & 15, g = lane >> 4, kl = g * 8;
  const int r0 = wave * 16;

  const float* Qb = Q + (size_t)blk * (S_ * D_);
  const short* Kb = Kfm + (size_t)blk * 8192;
  const short* Vb = Vfm + (size_t)blk * 8192;
  const short* Sb = Sfm + (size_t)blk * 16384;
  const short* Wh = Wfm + (size_t)h * 8192;
  const short* Zb = Zp + (size_t)blk * F2_;
  const float w = 1.f / (1.f + __expf(-alphap[0]));
  const f32x4 z4 = {0.f, 0.f, 0.f, 0.f};

  // ---- u = q @ W (save Q A-fragments for scores) ----
  s16x8 aq[4];
  f32x4 uacc[4] = {z4, z4, z4, z4};
  for (int ks = 0; ks < 4; ++ks) {
    aq[ks] = frag_f32(Qb + (size_t)(r0 + rl) * D_ + ks * 32 + kl);
#pragma unroll
    for (int tn = 0; tn < 4; ++tn) {
      s16x8 b = *(const s16x8*)(Wh + (((tn * 4 + ks)) << 9) + lane * 8);
      uacc[tn] = MFMA(aq[ks], b, uacc[tn]);
    }
  }

  // ---- phi_q (row-major, swizzled) ----
#pragma unroll
  for (int reg = 0; reg < 4; ++reg) {
    float mx = -1e30f, mn = 1e30f;
#pragma unroll
    for (int tn = 0; tn < 4; ++tn) {
      mx = fmaxf(mx, uacc[tn][reg]);
      mn = fminf(mn, uacc[tn][reg]);
    }
#pragma unroll
    for (int o = 1; o <= 8; o <<= 1) {
      mx = fmaxf(mx, __shfl_xor(mx, o, 64));
      mn = fminf(mn, __shfl_xor(mn, o, 64));
    }
    float ep[4], em[4], sp = 0.f, sm = 0.f;
#pragma unroll
    for (int tn = 0; tn < 4; ++tn) {
      ep[tn] = __expf(uacc[tn][reg] - mx); sp += ep[tn];
      em[tn] = __expf(mn - uacc[tn][reg]); sm += em[tn];
    }
#pragma unroll
    for (int o = 1; o <= 8; o <<= 1) {
      sp += __shfl_xor(sp, o, 64);
      sm += __shfl_xor(sm, o, 64);
    }
    const float rp = 1.f / sp, rm = 1.f / sm;
    const int srow = r0 + g * 4 + reg;
#pragma unroll
    for (int tn = 0; tn < 4; ++tn) {
      int f = tn * 16 + rl;
      lds_w16(phi, srow, 2 * F2_, f * 2,        f2bf(ep[tn] * rp));
      lds_w16(phi, srow, 2 * F2_, (f + 64) * 2, f2bf(em[tn] * rm));
    }
  }
  __syncthreads();

  // ---- cl[row] = (1-w)/max(phi·Zprefix, eps) ----
  if (tid < 64) {
    float den = 0.f;
#pragma unroll
    for (int j2 = 0; j2 < 16; ++j2) {
      s16x8 v = swz_frag(phi, tid, 2 * F2_, j2 * 16);
      s16x8 zv = *(const s16x8*)(Zb + j2 * 8);
#pragma unroll
      for (int e = 0; e < 8; ++e) den += bf2f(v[e]) * bf2f(zv[e]);
    }
    clL[tid] = (1.f - w) / fmaxf(den, EPS_);
  }

  // ---- scores = q @ k^T (Kfm dense), softmax, P*w -> Pl ----
  f32x4 sacc[4] = {z4, z4, z4, z4};
  for (int ks = 0; ks < 4; ++ks) {
#pragma unroll
    for (int tn = 0; tn < 4; ++tn) {
      s16x8 b = *(const s16x8*)(Kb + (((tn * 4 + ks)) << 9) + lane * 8);
      sacc[tn] = MFMA(aq[ks], b, sacc[tn]);
    }
  }
#pragma unroll
  for (int reg = 0; reg < 4; ++reg) {
    float mx = -1e30f;
#pragma unroll
    for (int tn = 0; tn < 4; ++tn) {
      sacc[tn][reg] *= SCALING_;
      mx = fmaxf(mx, sacc[tn][reg]);
    }
#pragma unroll
    for (int o = 1; o <= 8; o <<= 1) mx = fmaxf(mx, __shfl_xor(mx, o, 64));
    float e_[4], sum = 0.f;
#pragma unroll
    for (int tn = 0; tn < 4; ++tn) {
      e_[tn] = __expf(sacc[tn][reg] - mx);
      sum += e_[tn];
    }
#pragma unroll
    for (int o = 1; o <= 8; o <<= 1) sum += __shfl_xor(sum, o, 64);
    const float pw = w / sum;
    const int srow = r0 + g * 4 + reg;
#pragma unroll
    for (int tn = 0; tn < 4; ++tn)
      lds_w16(Pl, srow, 2 * S_, (tn * 16 + rl) * 2, f2bf(e_[tn] * pw));
  }
  __syncthreads();

  // ---- acc = phi @ St (Sfm dense), *cl ----
  f32x4 acc[8];
#pragma unroll
  for (int tn = 0; tn < 8; ++tn) acc[tn] = z4;

  for (int ks = 0; ks < 4; ++ks) {
    s16x8 a = swz_frag(phi, r0 + rl, 2 * F2_, (ks * 32 + kl) * 2);
#pragma unroll
    for (int tn = 0; tn < 8; ++tn) {
      s16x8 b = *(const s16x8*)(Sb + (((tn * 4 + ks)) << 9) + lane * 8);
      acc[tn] = MFMA(a, b, acc[tn]);
    }
  }
  float cl[4];
#pragma unroll
  for (int reg = 0; reg < 4; ++reg) cl[reg] = clL[r0 + g * 4 + reg];
#pragma unroll
  for (int tn = 0; tn < 8; ++tn)
#pragma unroll
    for (int reg = 0; reg < 4; ++reg) acc[tn][reg] *= cl[reg];

  // ---- acc += P @ V (Vfm dense) ----
  for (int ks = 0; ks < 2; ++ks) {
    s16x8 a = swz_frag(Pl, r0 + rl, 2 * S_, (ks * 32 + kl) * 2);
#pragma unroll
    for (int tn = 0; tn < 8; ++tn) {
      s16x8 b = *(const s16x8*)(Vb + (((tn * 2 + ks)) << 9) + lane * 8);
      acc[tn] = MFMA(a, b, acc[tn]);
    }
  }

  // ---- store ----
  float* Ob = Out + (size_t)blk * (S_ * D_);
#pragma unroll
  for (int tn = 0; tn < 8; ++tn)
#pragma unroll
    for (int reg = 0; reg < 4; ++reg) {
      int srow = r0 + g * 4 + reg;
      Ob[(size_t)srow * D_ + tn * 16 + rl] = acc[tn][reg];
    }
}

// ---------------------------------------------------------------------------
extern "C" void kernel_launch(void* const* d_in, const int* in_sizes, int n_in,
                              void* d_out, int out_size, void* d_ws, size_t ws_size,
                              hipStream_t stream)
{
  const float* Q = (const float*)d_in[0];
  const float* K = (const float*)d_in[1];
  const float* V = (const float*)d_in[2];
  const float* W = (const float*)d_in[3];
  const float* alpha = (const float*)d_in[4];
  float* Out = (float*)d_out;

  short* Vfm = (short*)d_ws;                             // 32 MiB
  short* Sfm = Vfm + (size_t)NBT_ * 8192;                // 64 MiB
  short* Kfm = Sfm + (size_t)NBT_ * 16384;               // 32 MiB
  short* dZ = Kfm + (size_t)NBT_ * 8192;                 // 0.5 MiB
  short* Wfm = dZ + (size_t)NBT_ * F2_;                  // 0.25 MiB
  // total 128.75 MiB (= R8's proven-available size)

  hipLaunchKernelGGL(prep_w, dim3(H_), dim3(256), 0, stream, W, Wfm);
  hipLaunchKernelGGL(bslh_phase1, dim3(NBT_), dim3(256), 0, stream,
                     K, V, Wfm, Vfm, Kfm, Sfm, dZ);
  hipLaunchKernelGGL(bslh_scan, dim3(516), dim3(256), 0, stream, Sfm, dZ);
  hipLaunchKernelGGL(bslh_phase3, dim3(NBT_), dim3(256), 0, stream,
                     Q, Kfm, Vfm, Wfm, Sfm, dZ, alpha, Out);
}

// Round 16
// 139.306 us; speedup vs baseline: 2.3721x; 1.0015x over previous
//
#include <hip/hip_runtime.h>
#include <math.h>

// Problem constants (fixed by reference)
#define B_ 2
#define H_ 16
#define L_ 4096
#define D_ 128
#define F_ 64
#define F2_ 128
#define S_ 64
#define N_ 64
#define BH_ 32
#define NBT_ 2048
#define EPS_ 1e-6f
#define SCALING_ 0.08838834764831845f  // 128^-0.5

typedef float f32x4 __attribute__((ext_vector_type(4)));
typedef short s16x8 __attribute__((ext_vector_type(8)));
typedef short s16x4 __attribute__((ext_vector_type(4)));

#define MFMA(a, b, c) __builtin_amdgcn_mfma_f32_16x16x32_bf16(a, b, c, 0, 0, 0)

// Fragment-major layout: per 64-token block, MFMA B/A fragments stored as
// contiguous 1KB units: unit (tn,ks), lane l=(g<<4)|rl holds 16B at l*16.
// Content: X[tn*16 + (l&15)][ks*32 + (l>>4)*8 + e], e=0..7 (bf16).

// Native bf16 casts: compiler emits v_cvt_pk_bf16_f32 (RNE) — no manual twiddle.
__device__ __forceinline__ short f2bf(float f) {
  __bf16 h = (__bf16)f;
  return __builtin_bit_cast(short, h);
}
__device__ __forceinline__ float bf2f(short s) {
  return __uint_as_float(((unsigned)(unsigned short)s) << 16);
}
__device__ __forceinline__ unsigned cvtpk2(float lo, float hi) {
  unsigned short a = __builtin_bit_cast(unsigned short, (__bf16)lo);
  unsigned short b = __builtin_bit_cast(unsigned short, (__bf16)hi);
  return (unsigned)a | ((unsigned)b << 16);
}
__device__ __forceinline__ s16x8 pack8(f32x4 a, f32x4 b) {
  union { unsigned u[4]; s16x8 s; } r;
  r.u[0] = cvtpk2(a[0], a[1]);
  r.u[1] = cvtpk2(a[2], a[3]);
  r.u[2] = cvtpk2(b[0], b[1]);
  r.u[3] = cvtpk2(b[2], b[3]);
  return r.s;
}
__device__ __forceinline__ s16x8 frag_f32(const float* p) {
  f32x4 a = *(const f32x4*)p;
  f32x4 b = *(const f32x4*)(p + 4);
  return pack8(a, b);
}

// XOR swizzle for generic LDS images: byte ^= (row&7)<<4 within a row.
__device__ __forceinline__ s16x8 swz_frag(const short* base, int row, int rowBytes, int colByte) {
  int byte = row * rowBytes + (colByte ^ ((row & 7) << 4));
  return *(const s16x8*)((const char*)base + byte);
}
__device__ __forceinline__ void lds_w16(short* lds, int row, int rowBytes, int colByte, short v) {
  int byte = row * rowBytes + (colByte ^ ((row & 7) << 4));
  *(short*)((char*)lds + byte) = v;
}

// VTs swizzle (mix two d-bit groups): writes spread over 8 bank-slots
// (16-way -> 4-way conflict); 16B-block alignment preserved for b128 reads.
__device__ __forceinline__ int vswz(int d, int colByte) {
  return d * 128 + (colByte ^ (((d ^ (d >> 2)) & 7) << 4));
}

// ---------------------------------------------------------------------------
// prep_w: Wfm[h] fragment-major (16 KB per h).
// ---------------------------------------------------------------------------
__global__ __launch_bounds__(256)
void prep_w(const float* __restrict__ W, short* __restrict__ Wfm)
{
  const int h = blockIdx.x;
  const int tid = threadIdx.x;
  const int f = tid & 63, gq = tid >> 6;   // gq = ks (d-chunk of 32)
  const float* Wh = W + (size_t)h * D_ * F_;
  short buf[32];
#pragma unroll
  for (int j = 0; j < 32; ++j) buf[j] = f2bf(Wh[(size_t)(gq * 32 + j) * F_ + f]);
  short* Wo = Wfm + (size_t)h * 8192 + ((((f >> 4) * 4 + gq)) << 9);
#pragma unroll
  for (int gp = 0; gp < 4; ++gp) {
    s16x8 v;
#pragma unroll
    for (int e = 0; e < 8; ++e) v[e] = buf[gp * 8 + e];
    *(s16x8*)(Wo + ((gp << 4) + (f & 15)) * 8) = v;
  }
}

// ---------------------------------------------------------------------------
// phase1: V->VTs image (gmix swizzle); u=k@W (Wfm dense); Kfm export from
// registers; phi_k -> phiT; dZ (bf16); dSt MFMA whose A-fragments ARE the
// Vfm units -> stored directly from registers; Sfm export via St image.
// ---------------------------------------------------------------------------
__global__ __launch_bounds__(256, 4)
void bslh_phase1(const float* __restrict__ K, const float* __restrict__ V,
                 const short* __restrict__ Wfm, short* __restrict__ Vfm,
                 short* __restrict__ Kfm, short* __restrict__ Sfm,
                 short* __restrict__ dZ)
{
  __shared__ __align__(16) char lds[32 * 1024];
  short* phiT = (short*)lds;              // 16KB [128 f][128B] swizzled
  short* VTs = (short*)(lds + 16384);     // 16KB [128 d][128B] gmix swizzled

  const int blk = blockIdx.x;
  const int bh = blk / N_;
  const int h = bh % H_;
  const int tid = threadIdx.x;
  const int wave = tid >> 6, lane = tid & 63;
  const int rl = lane & 15, g = lane >> 4, kl = g * 8;
  const int r0 = wave * 16;

  const float* Kb = K + (size_t)blk * (S_ * D_);
  const short* Wh = Wfm + (size_t)h * 8192;
  const f32x4 z4 = {0.f, 0.f, 0.f, 0.f};

  // ---- batch-issue V + K loads ----
  f32x4 vv[8];
  {
    const f32x4* gv = (const f32x4*)(V + (size_t)blk * S_ * D_);
#pragma unroll
    for (int ii = 0; ii < 8; ++ii) vv[ii] = gv[tid + 256 * ii];
  }
  f32x4 kv[8];
  {
    const float* kp = Kb + (size_t)(r0 + rl) * D_ + kl;
#pragma unroll
    for (int i = 0; i < 8; ++i) kv[i] = *(const f32x4*)(kp + (i >> 1) * 32 + (i & 1) * 4);
  }

  // ---- V transpose -> VTs image (gmix swizzle; s is even for active lanes) ----
#pragma unroll
  for (int ii = 0; ii < 8; ++ii) {
    int idx = tid + 256 * ii;
    int s = idx >> 5, c = (idx & 31) * 4;
    float m0 = vv[ii][0], m1 = vv[ii][1], m2 = vv[ii][2], m3 = vv[ii][3];
    float o0 = __shfl_xor(m0, 32, 64);
    float o1 = __shfl_xor(m1, 32, 64);
    float o2 = __shfl_xor(m2, 32, 64);
    float o3 = __shfl_xor(m3, 32, 64);
    if (!(tid & 32)) {
      float m[4] = {m0, m1, m2, m3};
      float o[4] = {o0, o1, o2, o3};
#pragma unroll
      for (int j = 0; j < 4; ++j) {
        int d = c + j;
        unsigned pk = cvtpk2(m[j], o[j]);
        *(unsigned*)((char*)VTs + vswz(d, s * 2)) = pk;
      }
    }
  }

  // ---- K fragments + Kfm export (coalesced 1KB stores) ----
  s16x8 aq[4];
#pragma unroll
  for (int ks = 0; ks < 4; ++ks) aq[ks] = pack8(kv[2 * ks], kv[2 * ks + 1]);
  {
    short* Ko = Kfm + (size_t)blk * 8192;
#pragma unroll
    for (int ks = 0; ks < 4; ++ks)
      *(s16x8*)(Ko + (((wave * 4 + ks)) << 9) + lane * 8) = aq[ks];
  }

  // ---- u = k @ W (dense Wfm reads) ----
  f32x4 uacc[4] = {z4, z4, z4, z4};
#pragma unroll
  for (int ks = 0; ks < 4; ++ks) {
#pragma unroll
    for (int tn = 0; tn < 4; ++tn) {
      s16x8 b = *(const s16x8*)(Wh + (((tn * 4 + ks)) << 9) + lane * 8);
      uacc[tn] = MFMA(aq[ks], b, uacc[tn]);
    }
  }

  // ---- phi_k = [softmax(u), softmax(-u)] -> phiT ----
#pragma unroll
  for (int reg = 0; reg < 4; ++reg) {
    float mx = -1e30f, mn = 1e30f;
#pragma unroll
    for (int tn = 0; tn < 4; ++tn) {
      mx = fmaxf(mx, uacc[tn][reg]);
      mn = fminf(mn, uacc[tn][reg]);
    }
#pragma unroll
    for (int o = 1; o <= 8; o <<= 1) {
      mx = fmaxf(mx, __shfl_xor(mx, o, 64));
      mn = fminf(mn, __shfl_xor(mn, o, 64));
    }
    float ep[4], em[4], sp = 0.f, sm = 0.f;
#pragma unroll
    for (int tn = 0; tn < 4; ++tn) {
      ep[tn] = __expf(uacc[tn][reg] - mx); sp += ep[tn];
      em[tn] = __expf(mn - uacc[tn][reg]); sm += em[tn];
    }
#pragma unroll
    for (int o = 1; o <= 8; o <<= 1) {
      sp += __shfl_xor(sp, o, 64);
      sm += __shfl_xor(sm, o, 64);
    }
    const float rp = 1.f / sp, rm = 1.f / sm;
    const int srow = r0 + g * 4 + reg;
#pragma unroll
    for (int tn = 0; tn < 4; ++tn) {
      int f = tn * 16 + rl;
      lds_w16(phiT, f,      2 * S_, srow * 2, f2bf(ep[tn] * rp));
      lds_w16(phiT, f + 64, 2 * S_, srow * 2, f2bf(em[tn] * rm));
    }
  }
  __syncthreads();   // phiT + VTs complete

  // ---- dZ[f] = colsum(phi_k) (bf16) ----
  {
    const int f = tid >> 1, half = tid & 1;
    float z = 0.f;
#pragma unroll
    for (int j2 = 0; j2 < 4; ++j2) {
      s16x8 v = swz_frag(phiT, f, 2 * S_, (half * 32 + j2 * 8) * 2);
#pragma unroll
      for (int e = 0; e < 8; ++e) z += bf2f(v[e]);
    }
    z += __shfl_xor(z, 1, 64);
    if (half == 0) dZ[(size_t)blk * F2_ + f] = f2bf(z);
  }

  // ---- dSt[d][f] MFMA; A-fragments ARE Vfm units (tn=2*wave+tm) ----
  f32x4 acc[2][8];
#pragma unroll
  for (int tm = 0; tm < 2; ++tm)
#pragma unroll
    for (int tn = 0; tn < 8; ++tn) acc[tm][tn] = z4;

  {
    short* Vo = Vfm + (size_t)blk * 8192;
#pragma unroll
    for (int ks = 0; ks < 2; ++ks) {
      s16x8 a[2];
#pragma unroll
      for (int tm = 0; tm < 2; ++tm) {
        int d = wave * 32 + tm * 16 + rl;
        a[tm] = *(const s16x8*)((const char*)VTs + vswz(d, (ks * 32 + kl) * 2));
        // store this Vfm unit (tn = 2*wave+tm, ks) straight from registers
        *(s16x8*)(Vo + ((((2 * wave + tm) * 2 + ks)) << 9) + lane * 8) = a[tm];
      }
#pragma unroll
      for (int tn = 0; tn < 8; ++tn) {
        s16x8 b = swz_frag(phiT, tn * 16 + rl, 2 * S_, (ks * 32 + kl) * 2);
#pragma unroll
        for (int tm = 0; tm < 2; ++tm)
          acc[tm][tn] = MFMA(a[tm], b, acc[tm][tn]);
      }
    }
  }
  __syncthreads();   // reuse lds as St image

  // ---- pack acc into St image [d-row 256B][f-col], swizzled ----
  short* Stb = (short*)lds;
#pragma unroll
  for (int tm = 0; tm < 2; ++tm)
#pragma unroll
    for (int tn = 0; tn < 8; ++tn)
#pragma unroll
      for (int reg = 0; reg < 4; ++reg) {
        float v0 = acc[tm][tn][reg];
        float v1 = __shfl_xor(v0, 1, 64);
        if (!(lane & 1)) {
          int drow = wave * 32 + tm * 16 + g * 4 + reg;
          int fcol = tn * 16 + rl;
          unsigned pk = cvtpk2(v0, v1);
          int byte = drow * 256 + ((fcol * 2) ^ ((drow & 7) << 4));
          *(unsigned*)((char*)Stb + byte) = pk;
        }
      }
  __syncthreads();

  // ---- Sfm export from St image (coalesced) ----
  {
    short* So = Sfm + (size_t)blk * 16384;
#pragma unroll
    for (int i = 0; i < 8; ++i) {
      int unit = i * 256 + tid;
      int l = unit & 63, ks = (unit >> 6) & 3, tn = unit >> 8;
      int d = tn * 16 + (l & 15);
      int fb = (ks * 32 + (l >> 4) * 8) * 2;
      s16x8 v = *(const s16x8*)((const char*)Stb + d * 256 + (fb ^ ((d & 7) << 4)));
      *(s16x8*)(So + unit * 8) = v;
    }
  }
}

// ---------------------------------------------------------------------------
// scan: blocks [0,512) -> exclusive prefix of Sfm in 4-short chunks
// (fragment-major is position-stable across n -> layout-agnostic);
// blocks [512,516) -> exclusive prefix of dZ (bf16).
// ---------------------------------------------------------------------------
__global__ __launch_bounds__(256)
void bslh_scan(short* __restrict__ St, short* __restrict__ dZ)
{
  const int tid = threadIdx.x;
  if (blockIdx.x < 512) {
    const int idx = blockIdx.x * 256 + tid;      // 131072 threads
    const int bh = idx >> 12;
    const int rem = idx & 4095;
    short* p = St + (size_t)bh * N_ * (F2_ * D_) + (size_t)rem * 4;
    float run[4] = {0.f, 0.f, 0.f, 0.f};
    for (int n = 0; n < N_; ++n) {
      s16x4 v = *(const s16x4*)p;
      s16x4 o;
#pragma unroll
      for (int e = 0; e < 4; ++e) {
        o[e] = f2bf(run[e]);
        run[e] += bf2f(v[e]);
      }
      *(s16x4*)p = o;
      p += F2_ * D_;
    }
  } else {
    const int idx = (blockIdx.x - 512) * 256 + tid;  // 1024 threads
    const int bh = idx >> 5, e = idx & 31;
    short* p = dZ + (size_t)bh * N_ * F2_ + (size_t)e * 4;
    float run[4] = {0.f, 0.f, 0.f, 0.f};
    for (int n = 0; n < N_; ++n) {
      s16x4 v = *(const s16x4*)p;
      s16x4 o;
#pragma unroll
      for (int e2 = 0; e2 < 4; ++e2) {
        o[e2] = f2bf(run[e2]);
        run[e2] += bf2f(v[e2]);
      }
      *(s16x4*)p = o;
      p += F2_;
    }
  }
}

// ---------------------------------------------------------------------------
// phase3 (fragment-major B-loads = contiguous 1KB per wave-load):
// u=q@W; phi_q; cl; scores (Kfm); P; lin (Sfm); PV (Vfm).
// ---------------------------------------------------------------------------
__global__ __launch_bounds__(256, 4)
void bslh_phase3(const float* __restrict__ Q, const short* __restrict__ Kfm,
                 const short* __restrict__ Vfm, const short* __restrict__ Wfm,
                 const short* __restrict__ Sfm, const short* __restrict__ Zp,
                 const float* __restrict__ alphap, float* __restrict__ Out)
{
  __shared__ __align__(16) short phi[S_ * F2_];  // 16KB [64][256B] swizzled
  __shared__ __align__(16) short Pl[S_ * S_];    // 8KB  [64][128B] swizzled
  __shared__ float clL[S_];

  const int blk = blockIdx.x;
  const int bh = blk / N_;
  const int h = bh % H_;
  const int tid = threadIdx.x;
  const int wave = tid >> 6, lane = tid & 63;
  const int rl = lane & 15, g = lane >> 4, kl = g * 8;
  const int r0 = wave * 16;

  const float* Qb = Q + (size_t)blk * (S_ * D_);
  const short* Kb = Kfm + (size_t)blk * 8192;
  const short* Vb = Vfm + (size_t)blk * 8192;
  const short* Sb = Sfm + (size_t)blk * 16384;
  const short* Wh = Wfm + (size_t)h * 8192;
  const short* Zb = Zp + (size_t)blk * F2_;
  const float w = 1.f / (1.f + __expf(-alphap[0]));
  const f32x4 z4 = {0.f, 0.f, 0.f, 0.f};

  // ---- u = q @ W (save Q A-fragments for scores) ----
  s16x8 aq[4];
  f32x4 uacc[4] = {z4, z4, z4, z4};
  for (int ks = 0; ks < 4; ++ks) {
    aq[ks] = frag_f32(Qb + (size_t)(r0 + rl) * D_ + ks * 32 + kl);
#pragma unroll
    for (int tn = 0; tn < 4; ++tn) {
      s16x8 b = *(const s16x8*)(Wh + (((tn * 4 + ks)) << 9) + lane * 8);
      uacc[tn] = MFMA(aq[ks], b, uacc[tn]);
    }
  }

  // ---- phi_q (row-major, swizzled) ----
#pragma unroll
  for (int reg = 0; reg < 4; ++reg) {
    float mx = -1e30f, mn = 1e30f;
#pragma unroll
    for (int tn = 0; tn < 4; ++tn) {
      mx = fmaxf(mx, uacc[tn][reg]);
      mn = fminf(mn, uacc[tn][reg]);
    }
#pragma unroll
    for (int o = 1; o <= 8; o <<= 1) {
      mx = fmaxf(mx, __shfl_xor(mx, o, 64));
      mn = fminf(mn, __shfl_xor(mn, o, 64));
    }
    float ep[4], em[4], sp = 0.f, sm = 0.f;
#pragma unroll
    for (int tn = 0; tn < 4; ++tn) {
      ep[tn] = __expf(uacc[tn][reg] - mx); sp += ep[tn];
      em[tn] = __expf(mn - uacc[tn][reg]); sm += em[tn];
    }
#pragma unroll
    for (int o = 1; o <= 8; o <<= 1) {
      sp += __shfl_xor(sp, o, 64);
      sm += __shfl_xor(sm, o, 64);
    }
    const float rp = 1.f / sp, rm = 1.f / sm;
    const int srow = r0 + g * 4 + reg;
#pragma unroll
    for (int tn = 0; tn < 4; ++tn) {
      int f = tn * 16 + rl;
      lds_w16(phi, srow, 2 * F2_, f * 2,        f2bf(ep[tn] * rp));
      lds_w16(phi, srow, 2 * F2_, (f + 64) * 2, f2bf(em[tn] * rm));
    }
  }
  __syncthreads();

  // ---- cl[row] = (1-w)/max(phi·Zprefix, eps) ----
  if (tid < 64) {
    float den = 0.f;
#pragma unroll
    for (int j2 = 0; j2 < 16; ++j2) {
      s16x8 v = swz_frag(phi, tid, 2 * F2_, j2 * 16);
      s16x8 zv = *(const s16x8*)(Zb + j2 * 8);
#pragma unroll
      for (int e = 0; e < 8; ++e) den += bf2f(v[e]) * bf2f(zv[e]);
    }
    clL[tid] = (1.f - w) / fmaxf(den, EPS_);
  }

  // ---- scores = q @ k^T (Kfm dense), softmax, P*w -> Pl ----
  f32x4 sacc[4] = {z4, z4, z4, z4};
  for (int ks = 0; ks < 4; ++ks) {
#pragma unroll
    for (int tn = 0; tn < 4; ++tn) {
      s16x8 b = *(const s16x8*)(Kb + (((tn * 4 + ks)) << 9) + lane * 8);
      sacc[tn] = MFMA(aq[ks], b, sacc[tn]);
    }
  }
#pragma unroll
  for (int reg = 0; reg < 4; ++reg) {
    float mx = -1e30f;
#pragma unroll
    for (int tn = 0; tn < 4; ++tn) {
      sacc[tn][reg] *= SCALING_;
      mx = fmaxf(mx, sacc[tn][reg]);
    }
#pragma unroll
    for (int o = 1; o <= 8; o <<= 1) mx = fmaxf(mx, __shfl_xor(mx, o, 64));
    float e_[4], sum = 0.f;
#pragma unroll
    for (int tn = 0; tn < 4; ++tn) {
      e_[tn] = __expf(sacc[tn][reg] - mx);
      sum += e_[tn];
    }
#pragma unroll
    for (int o = 1; o <= 8; o <<= 1) sum += __shfl_xor(sum, o, 64);
    const float pw = w / sum;
    const int srow = r0 + g * 4 + reg;
#pragma unroll
    for (int tn = 0; tn < 4; ++tn)
      lds_w16(Pl, srow, 2 * S_, (tn * 16 + rl) * 2, f2bf(e_[tn] * pw));
  }
  __syncthreads();

  // ---- acc = phi @ St (Sfm dense), *cl ----
  f32x4 acc[8];
#pragma unroll
  for (int tn = 0; tn < 8; ++tn) acc[tn] = z4;

  for (int ks = 0; ks < 4; ++ks) {
    s16x8 a = swz_frag(phi, r0 + rl, 2 * F2_, (ks * 32 + kl) * 2);
#pragma unroll
    for (int tn = 0; tn < 8; ++tn) {
      s16x8 b = *(const s16x8*)(Sb + (((tn * 4 + ks)) << 9) + lane * 8);
      acc[tn] = MFMA(a, b, acc[tn]);
    }
  }
  float cl[4];
#pragma unroll
  for (int reg = 0; reg < 4; ++reg) cl[reg] = clL[r0 + g * 4 + reg];
#pragma unroll
  for (int tn = 0; tn < 8; ++tn)
#pragma unroll
    for (int reg = 0; reg < 4; ++reg) acc[tn][reg] *= cl[reg];

  // ---- acc += P @ V (Vfm dense) ----
  for (int ks = 0; ks < 2; ++ks) {
    s16x8 a = swz_frag(Pl, r0 + rl, 2 * S_, (ks * 32 + kl) * 2);
#pragma unroll
    for (int tn = 0; tn < 8; ++tn) {
      s16x8 b = *(const s16x8*)(Vb + (((tn * 2 + ks)) << 9) + lane * 8);
      acc[tn] = MFMA(a, b, acc[tn]);
    }
  }

  // ---- store ----
  float* Ob = Out + (size_t)blk * (S_ * D_);
#pragma unroll
  for (int tn = 0; tn < 8; ++tn)
#pragma unroll
    for (int reg = 0; reg < 4; ++reg) {
      int srow = r0 + g * 4 + reg;
      Ob[(size_t)srow * D_ + tn * 16 + rl] = acc[tn][reg];
    }
}

// ---------------------------------------------------------------------------
extern "C" void kernel_launch(void* const* d_in, const int* in_sizes, int n_in,
                              void* d_out, int out_size, void* d_ws, size_t ws_size,
                              hipStream_t stream)
{
  const float* Q = (const float*)d_in[0];
  const float* K = (const float*)d_in[1];
  const float* V = (const float*)d_in[2];
  const float* W = (const float*)d_in[3];
  const float* alpha = (const float*)d_in[4];
  float* Out = (float*)d_out;

  short* Vfm = (short*)d_ws;                             // 32 MiB
  short* Sfm = Vfm + (size_t)NBT_ * 8192;                // 64 MiB
  short* Kfm = Sfm + (size_t)NBT_ * 16384;               // 32 MiB
  short* dZ = Kfm + (size_t)NBT_ * 8192;                 // 0.5 MiB
  short* Wfm = dZ + (size_t)NBT_ * F2_;                  // 0.25 MiB

  hipLaunchKernelGGL(prep_w, dim3(H_), dim3(256), 0, stream, W, Wfm);
  hipLaunchKernelGGL(bslh_phase1, dim3(NBT_), dim3(256), 0, stream,
                     K, V, Wfm, Vfm, Kfm, Sfm, dZ);
  hipLaunchKernelGGL(bslh_scan, dim3(516), dim3(256), 0, stream, Sfm, dZ);
  hipLaunchKernelGGL(bslh_phase3, dim3(NBT_), dim3(256), 0, stream,
                     Q, Kfm, Vfm, Wfm, Sfm, dZ, alpha, Out);
}